// Round 7
// baseline (131.256 us; speedup 1.0000x reference)
//
#include <hip/hip_runtime.h>

#define B_ 8
#define S_ 512
#define D_ 768
#define LAYER0 4
#define LSTRIDE4 (8*512*768/4)   // float4 between layers
#define SCH 32                   // pooling chunks per batch
#define CW (S_/SCH)              // 16 tokens per chunk

// upper-triangle pair q -> (i,j), i<=j, row-major
__device__ const int QI9[45] = {0,0,0,0,0,0,0,0,0, 1,1,1,1,1,1,1,1, 2,2,2,2,2,2,2,
                                3,3,3,3,3,3, 4,4,4,4,4, 5,5,5,5, 6,6,6, 7,7, 8};
__device__ const int QJ9[45] = {0,1,2,3,4,5,6,7,8, 1,2,3,4,5,6,7,8, 2,3,4,5,6,7,8,
                                3,4,5,6,7,8, 4,5,6,7,8, 5,6,7,8, 6,7,8, 7,8, 8};

__device__ __forceinline__ float dot4(const float4& a, const float4& b) {
  return fmaf(a.x, b.x, fmaf(a.y, b.y, fmaf(a.z, b.z, a.w * b.w)));
}

// ---------------- kernel 1: per-token Gram (f32, chunked) -> wa coefficients ----------------
__global__ __launch_bounds__(64, 4) void wk_token(const float* __restrict__ hid,
                                                  const int* __restrict__ mask,
                                                  float* __restrict__ wa) {
  const int token = blockIdx.x;        // b*S + s
  const int b = token >> 9;
  const int s = token & (S_ - 1);
  const int t = threadIdx.x;           // 0..63, one wave

  __shared__ float pgl[16][45];        // after 4-lane pre-reduce
  __shared__ float Gsym[81];
  __shared__ float st[19];             // align[0..8], nov[9..17], var[18]

  // mask is monotone (arange < length): s < len=length-1  <=>  mask[s+1]==1
  const int valid = (s < S_ - 1) ? mask[b * S_ + s + 1] : 0;

  // chunked pair-dot accumulation: keeps only 9 float4 + 45 partials live
  const float4* base = (const float4*)hid
      + (((size_t)LAYER0 * B_ + b) * S_ + s) * (D_ / 4) + t;
  float pp[45];
#pragma unroll
  for (int q = 0; q < 45; ++q) pp[q] = 0.f;

#pragma unroll
  for (int c = 0; c < 3; ++c) {
    float4 g[9];
#pragma unroll
    for (int l = 0; l < 9; ++l) g[l] = base[(size_t)l * LSTRIDE4 + c * 64];
    int q = 0;
#pragma unroll
    for (int i = 0; i < 9; ++i) {
#pragma unroll
      for (int j = i; j < 9; ++j) {
        pp[q] += dot4(g[i], g[j]);
        ++q;
      }
    }
  }

  // 4-lane pre-reduce, then lanes with t%4==0 write row t>>2
#pragma unroll
  for (int q = 0; q < 45; ++q) {
    pp[q] += __shfl_xor(pp[q], 1);
    pp[q] += __shfl_xor(pp[q], 2);
  }
  if ((t & 3) == 0) {
    const int r = t >> 2;
#pragma unroll
    for (int q = 0; q < 45; ++q) pgl[r][q] = pp[q];
  }
  __syncthreads();

  // column sums: lane q (<45) owns pair q; 2 accumulators
  if (t < 45) {
    float a0 = 0.f, a1 = 0.f;
#pragma unroll
    for (int r = 0; r < 16; r += 2) { a0 += pgl[r][t]; a1 += pgl[r + 1][t]; }
    float tot = a0 + a1;
    Gsym[QI9[t] * 9 + QJ9[t]] = tot;
    Gsym[QJ9[t] * 9 + QI9[t]] = tot;
  }
  __syncthreads();

  // lanes 0..8: per-k align/nov via Cholesky; lane 9: cosine variance -> LDS
  if (t < 9) {
    const int k = t;
    int nb[4]; int m = 0;
    if (k >= 2) { nb[m++] = k - 2; nb[m++] = k - 1; }
    if (k + 1 < 9) nb[m++] = k + 1;
    if (k + 2 < 9) nb[m++] = k + 2;
    const int n = m + 1;

    float g[4], Lc[4][4], tv[4];
    for (int i = 0; i < m; ++i) g[i] = Gsym[nb[i] * 9 + k];

    for (int i = 0; i < m; ++i) {
      for (int j = 0; j <= i; ++j) {
        float sum = Gsym[nb[i] * 9 + nb[j]];
        for (int p = 0; p < j; ++p) sum -= Lc[i][p] * Lc[j][p];
        Lc[i][j] = (i == j) ? sqrtf(sum) : sum / Lc[j][j];
      }
    }
    float s2 = 0.f;
    for (int i = 0; i < m; ++i) {
      float sum = g[i];
      for (int p = 0; p < i; ++p) sum -= Lc[i][p] * tv[p];
      tv[i] = sum / Lc[i][i];
      s2 += tv[i] * tv[i];
    }
    float ar = 0.f;
    for (int i = 0; i < m; ++i) ar += g[i] / sqrtf(Gsym[nb[i] * 9 + nb[i]]);
    ar /= (float)m;

    st[k] = sqrtf(s2) / (ar * (2.0f * (float)n));          // align
    float Gkk = Gsym[k * 9 + k];
    st[9 + k] = sqrtf(fmaxf(Gkk - s2, 0.f)) / sqrtf(Gkk);  // nov
  }
  if (t == 9) {
    float sc = 0.f, sc2 = 0.f;
    for (int i = 0; i < 8; ++i) {
      float nn = sqrtf(Gsym[i * 9 + i]) * sqrtf(Gsym[(i + 1) * 9 + i + 1]);
      nn = fmaxf(nn, 1e-8f);
      float ci = Gsym[i * 9 + i + 1] / nn;
      sc += ci; sc2 += ci * ci;
    }
    float mean = sc * 0.125f;
    st[18] = (sc2 - 8.f * mean * mean) * (1.f / 7.f);
  }
  __syncthreads();

  // lanes 0..8 write wa = alpha_norm * w (broadcast LDS reads, no reg-array dyn index)
  if (t < 9) {
    float sa = 0.f, sn = 0.f;
#pragma unroll
    for (int l = 0; l < 9; ++l) { sa += st[l]; sn += st[9 + l]; }
    const float rsa = 1.f / sa, rsn = 1.f / sn;
    float ss = 0.f;
#pragma unroll
    for (int l = 0; l < 9; ++l) ss += st[l] * rsa + st[9 + l] * rsn;
    const float w = valid ? st[18] : 0.f;
    const float al = st[t] * rsa + st[9 + t] * rsn;
    wa[token * 9 + t] = al * (w / ss);
  }
}

// ---------------- kernel 2: pooled einsum directly from input (L3-resident) ----------------
// P[b,c,:] = sum_{s in chunk} sum_l wa[s][l] * F[l][b][s][:];  Pw = sum wa (= sum w)
__global__ __launch_bounds__(192) void wk_pool(const float* __restrict__ hid,
                                               const float* __restrict__ wa,
                                               float* __restrict__ P,
                                               float* __restrict__ Pw) {
  const int b = blockIdx.x >> 5;
  const int c = blockIdx.x & 31;
  const int t = threadIdx.x;

  __shared__ float ca[CW][9];
  if (t < CW * 9) ((float*)ca)[t] = wa[((size_t)b * S_ + c * CW) * 9 + t];
  __syncthreads();

  float4 a = make_float4(0.f, 0.f, 0.f, 0.f);
  const float4* base = (const float4*)hid
      + (((size_t)LAYER0 * B_ + b) * S_ + c * CW) * (D_ / 4) + t;
#pragma unroll
  for (int l = 0; l < 9; ++l) {
#pragma unroll 4
    for (int sl = 0; sl < CW; ++sl) {
      float wgt = ca[sl][l];
      float4 p = base[(size_t)l * LSTRIDE4 + sl * (D_ / 4)];
      a.x += wgt * p.x; a.y += wgt * p.y; a.z += wgt * p.z; a.w += wgt * p.w;
    }
  }
  ((float4*)P)[(size_t)blockIdx.x * (D_ / 4) + t] = a;
  if (t == 0) {
    float ws = 0.f;
#pragma unroll
    for (int sl = 0; sl < CW; ++sl)
#pragma unroll
      for (int l = 0; l < 9; ++l) ws += ca[sl][l];
    Pw[blockIdx.x] = ws;
  }
}

// ---------------- kernel 3: combine partials, divide by weight sum ----------------
__global__ __launch_bounds__(256) void wk_pool_final(const float* __restrict__ P,
                                                     const float* __restrict__ Pw,
                                                     float* __restrict__ out) {
  const int i = blockIdx.x * 256 + threadIdx.x;   // 0 .. B*(D/4)-1 = 1535
  const int b = i / (D_ / 4);
  const int d4 = i % (D_ / 4);
  float n0 = 0.f, n1 = 0.f, n2 = 0.f, n3 = 0.f, den = 0.f;
#pragma unroll
  for (int c = 0; c < SCH; ++c) {
    float4 p = ((const float4*)P)[((size_t)b * SCH + c) * (D_ / 4) + d4];
    n0 += p.x; n1 += p.y; n2 += p.z; n3 += p.w;
    den += Pw[b * SCH + c];
  }
  float inv = 1.f / den;
  ((float4*)out)[i] = make_float4(n0 * inv, n1 * inv, n2 * inv, n3 * inv);
}

extern "C" void kernel_launch(void* const* d_in, const int* in_sizes, int n_in,
                              void* d_out, int out_size, void* d_ws, size_t ws_size,
                              hipStream_t stream) {
  const float* hid = (const float*)d_in[0];       // (13, 8, 512, 768) f32
  const int* mask = (const int*)d_in[1];          // (8, 512) i32
  float* out = (float*)d_out;                     // (8, 768) f32

  float* wa = (float*)d_ws;                       // B*S*9 coefficients (alpha_norm * w)
  float* P  = wa + (size_t)B_ * S_ * 9;           // B*SCH*D partials
  float* Pw = P + (size_t)B_ * SCH * D_;          // B*SCH partial weight sums

  wk_token<<<B_ * S_, 64, 0, stream>>>(hid, mask, wa);
  wk_pool<<<B_ * SCH, 192, 0, stream>>>(hid, wa, P, Pw);
  wk_pool_final<<<(B_ * (D_ / 4) + 255) / 256, 256, 0, stream>>>(P, Pw, out);
}

// Round 8
// 112.679 us; speedup vs baseline: 1.1649x; 1.1649x over previous
//
#include <hip/hip_runtime.h>

#define B_ 8
#define S_ 512
#define D_ 768
#define D4 (D_/4)                 // 192 float4 per token vector
#define LAYER0 4
#define LSTRIDE4 (8*512*768/4)    // float4 between layers
#define CPB 128                   // 4-token blocks per batch (512/4)

// upper-triangle pair q -> (i,j), i<=j, row-major
__device__ const int QI9[45] = {0,0,0,0,0,0,0,0,0, 1,1,1,1,1,1,1,1, 2,2,2,2,2,2,2,
                                3,3,3,3,3,3, 4,4,4,4,4, 5,5,5,5, 6,6,6, 7,7, 8};
__device__ const int QJ9[45] = {0,1,2,3,4,5,6,7,8, 1,2,3,4,5,6,7,8, 2,3,4,5,6,7,8,
                                3,4,5,6,7,8, 4,5,6,7,8, 5,6,7,8, 6,7,8, 7,8, 8};

__device__ __forceinline__ float dot4(const float4& a, const float4& b) {
  return fmaf(a.x, b.x, fmaf(a.y, b.y, fmaf(a.z, b.z, a.w * b.w)));
}

// ---------------- fused kernel: Gram + alpha + weighted te + in-block pool ----------------
// 256 threads = 4 waves = 4 consecutive tokens; one 768-f32 partial per block.
__global__ __launch_bounds__(256, 3) void wk_main(const float* __restrict__ hid,
                                                  const int* __restrict__ mask,
                                                  float* __restrict__ P,
                                                  float* __restrict__ Pw) {
  const int blk = blockIdx.x;            // 0..1023
  const int wid = threadIdx.x >> 6;
  const int lane = threadIdx.x & 63;
  const int token = blk * 4 + wid;       // b*S + s
  const int b = token >> 9, s = token & (S_ - 1);

  __shared__ float pgl[4][64][45];       // 46 KB; aliased as teacc after column reduce
  __shared__ float Gsym[4][81];
  __shared__ float st[4][19];            // align[0..8], nov[9..17], var[18]
  __shared__ float wl[4];

  // mask is monotone (arange < length): s < len=length-1  <=>  mask[s+1]==1
  const int valid = (s < S_ - 1) ? mask[b * S_ + s + 1] : 0;

  // 27 coalesced dwordx4 loads, all in flight (dims t, t+64, t+128 per layer)
  const float4* base = (const float4*)hid
      + (((size_t)LAYER0 * B_ + b) * S_ + s) * D4 + lane;
  float4 f[27];
#pragma unroll
  for (int l = 0; l < 9; ++l) {
#pragma unroll
    for (int c = 0; c < 3; ++c) f[l * 3 + c] = base[(size_t)l * LSTRIDE4 + c * 64];
  }

  // 45 pair partial dots, written straight to LDS (no big live reg array)
  {
    int q = 0;
#pragma unroll
    for (int i = 0; i < 9; ++i) {
#pragma unroll
      for (int j = i; j < 9; ++j) {
        pgl[wid][lane][q] = dot4(f[i * 3], f[j * 3])
                          + dot4(f[i * 3 + 1], f[j * 3 + 1])
                          + dot4(f[i * 3 + 2], f[j * 3 + 2]);
        ++q;
      }
    }
  }
  __syncthreads();

  // column sums: each wave reduces its own token; 4 accumulators break FP chain
  if (lane < 45) {
    float a0 = 0.f, a1 = 0.f, a2 = 0.f, a3 = 0.f;
#pragma unroll
    for (int r = 0; r < 64; r += 4) {
      a0 += pgl[wid][r][lane];     a1 += pgl[wid][r + 1][lane];
      a2 += pgl[wid][r + 2][lane]; a3 += pgl[wid][r + 3][lane];
    }
    float tot = (a0 + a1) + (a2 + a3);
    Gsym[wid][QI9[lane] * 9 + QJ9[lane]] = tot;
    Gsym[wid][QJ9[lane] * 9 + QI9[lane]] = tot;
  }
  __syncthreads();

  // lanes 0..8 of each wave: per-k align/nov via Cholesky; lane 9: cosine variance
  if (lane < 9) {
    const int k = lane;
    int nb[4]; int m = 0;
    if (k >= 2) { nb[m++] = k - 2; nb[m++] = k - 1; }
    if (k + 1 < 9) nb[m++] = k + 1;
    if (k + 2 < 9) nb[m++] = k + 2;
    const int n = m + 1;

    float g[4], Lc[4][4], tv[4];
    for (int i = 0; i < m; ++i) g[i] = Gsym[wid][nb[i] * 9 + k];

    for (int i = 0; i < m; ++i) {
      for (int j = 0; j <= i; ++j) {
        float sum = Gsym[wid][nb[i] * 9 + nb[j]];
        for (int p = 0; p < j; ++p) sum -= Lc[i][p] * Lc[j][p];
        Lc[i][j] = (i == j) ? sqrtf(sum) : sum / Lc[j][j];
      }
    }
    float s2 = 0.f;
    for (int i = 0; i < m; ++i) {
      float sum = g[i];
      for (int p = 0; p < i; ++p) sum -= Lc[i][p] * tv[p];
      tv[i] = sum / Lc[i][i];
      s2 += tv[i] * tv[i];
    }
    float ar = 0.f;
    for (int i = 0; i < m; ++i) ar += g[i] / sqrtf(Gsym[wid][nb[i] * 9 + nb[i]]);
    ar /= (float)m;

    st[wid][k] = sqrtf(s2) / (ar * (2.0f * (float)n));           // align
    float Gkk = Gsym[wid][k * 9 + k];
    st[wid][9 + k] = sqrtf(fmaxf(Gkk - s2, 0.f)) / sqrtf(Gkk);   // nov
  }
  if (lane == 9) {
    float sc = 0.f, sc2 = 0.f;
    for (int i = 0; i < 8; ++i) {
      float nn = sqrtf(Gsym[wid][i * 9 + i]) * sqrtf(Gsym[wid][(i + 1) * 9 + i + 1]);
      nn = fmaxf(nn, 1e-8f);
      float ci = Gsym[wid][i * 9 + i + 1] / nn;
      sc += ci; sc2 += ci * ci;
    }
    float mean = sc * 0.125f;
    st[wid][18] = (sc2 - 8.f * mean * mean) * (1.f / 7.f);
  }
  __syncthreads();

  // epilogue: all lanes, broadcast LDS reads; weighted token emb from registers
  const float w = valid ? st[wid][18] : 0.f;
  float sa = 0.f, sn = 0.f;
#pragma unroll
  for (int l = 0; l < 9; ++l) { sa += st[wid][l]; sn += st[wid][9 + l]; }
  const float rsa = 1.f / sa, rsn = 1.f / sn;
  float a9[9]; float ss = 0.f;
#pragma unroll
  for (int l = 0; l < 9; ++l) { a9[l] = st[wid][l] * rsa + st[wid][9 + l] * rsn; ss += a9[l]; }
  const float inv = w / ss;

  float4 acc0 = {0,0,0,0}, acc1 = {0,0,0,0}, acc2 = {0,0,0,0};
#pragma unroll
  for (int l = 0; l < 9; ++l) {
    const float a = a9[l] * inv;
    acc0.x += a * f[l*3].x;   acc0.y += a * f[l*3].y;   acc0.z += a * f[l*3].z;   acc0.w += a * f[l*3].w;
    acc1.x += a * f[l*3+1].x; acc1.y += a * f[l*3+1].y; acc1.z += a * f[l*3+1].z; acc1.w += a * f[l*3+1].w;
    acc2.x += a * f[l*3+2].x; acc2.y += a * f[l*3+2].y; acc2.z += a * f[l*3+2].z; acc2.w += a * f[l*3+2].w;
  }

  // pgl is dead -> alias as per-wave te accumulator [4][192] float4
  float4* teacc = (float4*)&pgl[0][0][0];
  teacc[wid * D4 + 0 * 64 + lane] = acc0;
  teacc[wid * D4 + 1 * 64 + lane] = acc1;
  teacc[wid * D4 + 2 * 64 + lane] = acc2;
  if (lane == 0) wl[wid] = w;
  __syncthreads();

  // cross-wave reduce: threads 0..191 sum the 4 waves' te, write block partial
  const int i = threadIdx.x;
  if (i < D4) {
    float4 r0 = teacc[i], r1 = teacc[D4 + i], r2 = teacc[2 * D4 + i], r3 = teacc[3 * D4 + i];
    float4 rr = make_float4((r0.x + r1.x) + (r2.x + r3.x),
                            (r0.y + r1.y) + (r2.y + r3.y),
                            (r0.z + r1.z) + (r2.z + r3.z),
                            (r0.w + r1.w) + (r2.w + r3.w));
    ((float4*)P)[(size_t)blk * D4 + i] = rr;
  }
  if (i == 192) Pw[blk] = (wl[0] + wl[1]) + (wl[2] + wl[3]);
}

// ---------------- final: combine 128 partials per batch, divide by weight sum ----------------
__global__ __launch_bounds__(64) void wk_final(const float* __restrict__ P,
                                               const float* __restrict__ Pw,
                                               float* __restrict__ out) {
  const int blk = blockIdx.x;              // 24 = B_ * 3
  const int b = blk / 3;
  const int i = (blk % 3) * 64 + threadIdx.x;   // float4 index 0..191

  float d0 = 0.f, d1 = 0.f;
#pragma unroll 8
  for (int c = 0; c < CPB; c += 2) { d0 += Pw[b * CPB + c]; d1 += Pw[b * CPB + c + 1]; }
  const float den = d0 + d1;

  float4 n = {0.f, 0.f, 0.f, 0.f};
  const float4* p = (const float4*)P + (size_t)b * CPB * D4 + i;
#pragma unroll 8
  for (int c = 0; c < CPB; ++c) {
    float4 v = p[(size_t)c * D4];
    n.x += v.x; n.y += v.y; n.z += v.z; n.w += v.w;
  }
  const float r = 1.f / den;
  ((float4*)out)[b * D4 + i] = make_float4(n.x * r, n.y * r, n.z * r, n.w * r);
}

extern "C" void kernel_launch(void* const* d_in, const int* in_sizes, int n_in,
                              void* d_out, int out_size, void* d_ws, size_t ws_size,
                              hipStream_t stream) {
  const float* hid = (const float*)d_in[0];       // (13, 8, 512, 768) f32
  const int* mask = (const int*)d_in[1];          // (8, 512) i32
  float* out = (float*)d_out;                     // (8, 768) f32

  float* P  = (float*)d_ws;                       // 1024 * 768 partials (3 MB)
  float* Pw = P + (size_t)B_ * CPB * D_;          // 1024 weight sums

  wk_main<<<B_ * CPB, 256, 0, stream>>>(hid, mask, P, Pw);
  wk_final<<<B_ * 3, 64, 0, stream>>>(P, Pw, out);
}

// Round 9
// 61.549 us; speedup vs baseline: 2.1326x; 1.8307x over previous
//
#include <hip/hip_runtime.h>

#define B_ 8
#define S_ 512
#define D_ 768
#define D4 (D_/4)                // 192 float4 per token vector
#define LAYER0 4
#define LSTRIDE4 (8*512*768/4)   // float4 between layers
#define SCH 32                   // pooling chunks per batch
#define CW (S_/SCH)              // 16 tokens per chunk

// upper-triangle pair q -> (i,j), i<=j, row-major
__device__ const int QI9[45] = {0,0,0,0,0,0,0,0,0, 1,1,1,1,1,1,1,1, 2,2,2,2,2,2,2,
                                3,3,3,3,3,3, 4,4,4,4,4, 5,5,5,5, 6,6,6, 7,7, 8};
__device__ const int QJ9[45] = {0,1,2,3,4,5,6,7,8, 1,2,3,4,5,6,7,8, 2,3,4,5,6,7,8,
                                3,4,5,6,7,8, 4,5,6,7,8, 5,6,7,8, 6,7,8, 7,8, 8};

__device__ __forceinline__ float dot4(const float4& a, const float4& b) {
  return fmaf(a.x, b.x, fmaf(a.y, b.y, fmaf(a.z, b.z, a.w * b.w)));
}

// ---------------- kernel 1: per-token Gram, 192 thr / 3 waves / 1 float4 per lane ----------------
__global__ __launch_bounds__(192) void wk_token(const float* __restrict__ hid,
                                                const int* __restrict__ mask,
                                                float* __restrict__ wte,
                                                float* __restrict__ wv) {
  const int token = blockIdx.x;        // b*S + s
  const int b = token >> 9;
  const int s = token & (S_ - 1);
  const int t = threadIdx.x;           // 0..191

  __shared__ float pgl[48][45];        // after 4-lane pre-reduce (8.6 KB)
  __shared__ float Gsym[81];
  __shared__ float st[19];             // align[0..8], nov[9..17], var[18]

  // mask is monotone (arange < length): s < len=length-1  <=>  mask[s+1]==1
  const int valid = (s < S_ - 1) ? mask[b * S_ + s + 1] : 0;

  // each lane owns dims 4t..4t+3: ONE float4 per layer -> f[9] = 36 VGPR live
  const float4* base = (const float4*)hid
      + (((size_t)LAYER0 * B_ + b) * S_ + s) * D4 + t;
  float4 f[9];
#pragma unroll
  for (int l = 0; l < 9; ++l) f[l] = base[(size_t)l * LSTRIDE4];

  // 45 pair dots: dot4 + 4-lane shfl pre-reduce, one value live at a time
  {
    int q = 0;
#pragma unroll
    for (int i = 0; i < 9; ++i) {
#pragma unroll
      for (int j = i; j < 9; ++j) {
        float v = dot4(f[i], f[j]);
        v += __shfl_xor(v, 1);
        v += __shfl_xor(v, 2);
        if ((t & 3) == 0) pgl[t >> 2][q] = v;
        ++q;
      }
    }
  }
  __syncthreads();

  // column sums: thread q (<45) sums 48 rows; 4 accumulators break the FP chain
  if (t < 45) {
    float a0 = 0.f, a1 = 0.f, a2 = 0.f, a3 = 0.f;
#pragma unroll
    for (int r = 0; r < 48; r += 4) {
      a0 += pgl[r][t];     a1 += pgl[r + 1][t];
      a2 += pgl[r + 2][t]; a3 += pgl[r + 3][t];
    }
    float tot = (a0 + a1) + (a2 + a3);
    Gsym[QI9[t] * 9 + QJ9[t]] = tot;
    Gsym[QJ9[t] * 9 + QI9[t]] = tot;
  }
  __syncthreads();

  // threads 0..8: per-k align/nov via Cholesky; thread 9: cosine variance
  if (t < 9) {
    const int k = t;
    int nb[4]; int m = 0;
    if (k >= 2) { nb[m++] = k - 2; nb[m++] = k - 1; }
    if (k + 1 < 9) nb[m++] = k + 1;
    if (k + 2 < 9) nb[m++] = k + 2;
    const int n = m + 1;

    float g[4], Lc[4][4], tv[4];
    for (int i = 0; i < m; ++i) g[i] = Gsym[nb[i] * 9 + k];

    for (int i = 0; i < m; ++i) {
      for (int j = 0; j <= i; ++j) {
        float sum = Gsym[nb[i] * 9 + nb[j]];
        for (int p = 0; p < j; ++p) sum -= Lc[i][p] * Lc[j][p];
        Lc[i][j] = (i == j) ? sqrtf(sum) : sum / Lc[j][j];
      }
    }
    float s2 = 0.f;
    for (int i = 0; i < m; ++i) {
      float sum = g[i];
      for (int p = 0; p < i; ++p) sum -= Lc[i][p] * tv[p];
      tv[i] = sum / Lc[i][i];
      s2 += tv[i] * tv[i];
    }
    float ar = 0.f;
    for (int i = 0; i < m; ++i) ar += g[i] / sqrtf(Gsym[nb[i] * 9 + nb[i]]);
    ar /= (float)m;

    st[k] = sqrtf(s2) / (ar * (2.0f * (float)n));          // align
    float Gkk = Gsym[k * 9 + k];
    st[9 + k] = sqrtf(fmaxf(Gkk - s2, 0.f)) / sqrtf(Gkk);  // nov
  }
  if (t == 9) {
    float sc = 0.f, sc2 = 0.f;
    for (int i = 0; i < 8; ++i) {
      float nn = sqrtf(Gsym[i * 9 + i]) * sqrtf(Gsym[(i + 1) * 9 + i + 1]);
      nn = fmaxf(nn, 1e-8f);
      float ci = Gsym[i * 9 + i + 1] / nn;
      sc += ci; sc2 += ci * ci;
    }
    float mean = sc * 0.125f;
    st[18] = (sc2 - 8.f * mean * mean) * (1.f / 7.f);
  }
  __syncthreads();

  // all threads: redundant scalar epilogue from broadcast LDS reads; write w * te
  const float w = valid ? st[18] : 0.f;
  float sa = 0.f, sn = 0.f;
#pragma unroll
  for (int l = 0; l < 9; ++l) { sa += st[l]; sn += st[9 + l]; }
  const float rsa = 1.f / sa, rsn = 1.f / sn;
  float a9[9]; float ss = 0.f;
#pragma unroll
  for (int l = 0; l < 9; ++l) { a9[l] = st[l] * rsa + st[9 + l] * rsn; ss += a9[l]; }
  const float inv = w / ss;

  float4 acc = {0.f, 0.f, 0.f, 0.f};
#pragma unroll
  for (int l = 0; l < 9; ++l) {
    const float a = a9[l] * inv;
    acc.x += a * f[l].x; acc.y += a * f[l].y; acc.z += a * f[l].z; acc.w += a * f[l].w;
  }
  ((float4*)wte)[(size_t)token * D4 + t] = acc;
  if (t == 0) wv[token] = w;
}

// ---------------- kernel 2: plain partial sums over 16-token chunks ----------------
__global__ __launch_bounds__(192) void wk_pool(const float* __restrict__ wte,
                                               const float* __restrict__ wv,
                                               float* __restrict__ P,
                                               float* __restrict__ Pw) {
  const int b = blockIdx.x >> 5;
  const int c = blockIdx.x & 31;
  const int t = threadIdx.x;

  float4 a = make_float4(0.f, 0.f, 0.f, 0.f);
  const float4* base = (const float4*)wte + ((size_t)b * S_ + c * CW) * D4 + t;
#pragma unroll 4
  for (int sl = 0; sl < CW; ++sl) {
    float4 p = base[sl * D4];
    a.x += p.x; a.y += p.y; a.z += p.z; a.w += p.w;
  }
  ((float4*)P)[(size_t)blockIdx.x * D4 + t] = a;
  if (t == 0) {
    float ws = 0.f;
#pragma unroll
    for (int i = 0; i < CW; ++i) ws += wv[b * S_ + c * CW + i];
    Pw[blockIdx.x] = ws;
  }
}

// ---------------- kernel 3: combine partials, divide by weight sum ----------------
__global__ __launch_bounds__(256) void wk_pool_final(const float* __restrict__ P,
                                                     const float* __restrict__ Pw,
                                                     float* __restrict__ out) {
  const int i = blockIdx.x * 256 + threadIdx.x;   // 0 .. B*D4-1 = 1535
  const int b = i / D4;
  const int d4 = i % D4;
  float n0 = 0.f, n1 = 0.f, n2 = 0.f, n3 = 0.f, den = 0.f;
#pragma unroll
  for (int c = 0; c < SCH; ++c) {
    float4 p = ((const float4*)P)[((size_t)b * SCH + c) * D4 + d4];
    n0 += p.x; n1 += p.y; n2 += p.z; n3 += p.w;
    den += Pw[b * SCH + c];
  }
  float inv = 1.f / den;
  ((float4*)out)[i] = make_float4(n0 * inv, n1 * inv, n2 * inv, n3 * inv);
}

extern "C" void kernel_launch(void* const* d_in, const int* in_sizes, int n_in,
                              void* d_out, int out_size, void* d_ws, size_t ws_size,
                              hipStream_t stream) {
  const float* hid = (const float*)d_in[0];       // (13, 8, 512, 768) f32
  const int* mask = (const int*)d_in[1];          // (8, 512) i32
  float* out = (float*)d_out;                     // (8, 768) f32

  float* wte = (float*)d_ws;                      // B*S*D  (w * token_emb)
  float* wv  = wte + (size_t)B_ * S_ * D_;        // B*S    (token weights)
  float* P   = wv + B_ * S_;                      // B*SCH*D
  float* Pw  = P + (size_t)B_ * SCH * D_;         // B*SCH

  wk_token<<<B_ * S_, 192, 0, stream>>>(hid, mask, wte, wv);
  wk_pool<<<B_ * SCH, 192, 0, stream>>>(wte, wv, P, Pw);
  wk_pool_final<<<(B_ * D4 + 255) / 256, 256, 0, stream>>>(P, Pw, out);
}